// Round 12
// baseline (139.134 us; speedup 1.0000x reference)
//
#include <hip/hip_runtime.h>
#include <hip/hip_bf16.h>
#include <math.h>

typedef float f32x16 __attribute__((ext_vector_type(16)));
typedef int   i32x4 __attribute__((ext_vector_type(4)));
typedef int   i32x8 __attribute__((ext_vector_type(8)));

#define BSZ 8192
#define DIM 2048
#define NTILE 64           // 8192 / 128 tiles per side
#define NKG 16             // k-groups of 128 elements (2 mfma-K each)

// MX e8m0 scale byte for 2^-6 (inputs pre-scaled by 64): 127-6 = 121 = 0x79
#define SCALE_I32 0x79797979

// Fragment-major fp4 layout for 32x32x64 mfma:
//   frag32(g2, R32) = 1024 B;  g2 = k/64 (0..31), R32 = row/32 (0..255)
//   frag base byte = ((g2 << 8) + R32) << 10
//   lane l at byte l*16, holding row R32*32 + (l&31),
//   k elems g2*64 + (l>>5)*32 .. +31 (2 elems/byte, ascending)
// One global_load_dwordx4 per lane = one fragment, fully coalesced (1 KB).
// (If the HW k-half<->lane-half mapping is swapped, it is swapped identically
//  for A and B, so the dot product is unchanged; C/D mapping is HW-verified.)

// ---------- e2m1 fp4 encode (round to nearest) ----------
__device__ __forceinline__ unsigned f2fp4(float v) {
  float a = fabsf(v);
  unsigned s = (__float_as_uint(v) >> 31) << 3;
  unsigned m = (a < 0.25f) ? 0u
             : (a < 0.75f) ? 1u
             : (a < 1.25f) ? 2u
             : (a < 1.75f) ? 3u
             : (a < 2.5f)  ? 4u
             : (a < 3.5f)  ? 5u
             : (a < 5.0f)  ? 6u : 7u;
  return s | m;
}

// ---------- kernel 1: fused normalize -> fp4(x*64) in frag32 order, diag ----------
__global__ void __launch_bounds__(256) k_prep(const float* __restrict__ X,
                                              const float* __restrict__ Y,
                                              unsigned char* __restrict__ Xq,
                                              unsigned char* __restrict__ Yq,
                                              float* __restrict__ dg) {
  const int row = blockIdx.x;
  const int tid = threadIdx.x;
  const float4* xp = (const float4*)(X + (size_t)row * DIM);
  const float4* yp = (const float4*)(Y + (size_t)row * DIM);
  float4 x0 = xp[tid * 2], x1 = xp[tid * 2 + 1];
  float4 y0 = yp[tid * 2], y1 = yp[tid * 2 + 1];
  float sxx = x0.x*x0.x + x0.y*x0.y + x0.z*x0.z + x0.w*x0.w
            + x1.x*x1.x + x1.y*x1.y + x1.z*x1.z + x1.w*x1.w;
  float syy = y0.x*y0.x + y0.y*y0.y + y0.z*y0.z + y0.w*y0.w
            + y1.x*y1.x + y1.y*y1.y + y1.z*y1.z + y1.w*y1.w;
  float sxy = x0.x*y0.x + x0.y*y0.y + x0.z*y0.z + x0.w*y0.w
            + x1.x*y1.x + x1.y*y1.y + x1.z*y1.z + x1.w*y1.w;
#pragma unroll
  for (int m = 32; m >= 1; m >>= 1) {
    sxx += __shfl_xor(sxx, m);
    syy += __shfl_xor(syy, m);
    sxy += __shfl_xor(sxy, m);
  }
  __shared__ float sh[3][4];
  if ((tid & 63) == 0) {
    sh[0][tid >> 6] = sxx; sh[1][tid >> 6] = syy; sh[2][tid >> 6] = sxy;
  }
  __syncthreads();
  float xx = sh[0][0] + sh[0][1] + sh[0][2] + sh[0][3];
  float yy = sh[1][0] + sh[1][1] + sh[1][2] + sh[1][3];
  float xy = sh[2][0] + sh[2][1] + sh[2][2] + sh[2][3];
  float nx = fmaxf(sqrtf(xx), 1e-8f);
  float ny = fmaxf(sqrtf(yy), 1e-8f);
  float ix = 64.0f / nx, iy = 64.0f / ny;   // x64 pre-scale onto e2m1 grid
  float vx[8] = {x0.x, x0.y, x0.z, x0.w, x1.x, x1.y, x1.z, x1.w};
  float vy[8] = {y0.x, y0.y, y0.z, y0.w, y1.x, y1.y, y1.z, y1.w};
  unsigned ux = 0, uy = 0;
#pragma unroll
  for (int i = 0; i < 8; ++i) {
    ux |= f2fp4(vx[i] * ix) << (4 * i);
    uy |= f2fp4(vy[i] * iy) << (4 * i);
  }
  // thread tid covers elems e = tid*8 .. +7 of this row
  const unsigned g2    = tid >> 3;          // e/64
  const unsigned khalf = (tid >> 2) & 1;    // (e%64)/32
  const unsigned byt   = (tid & 3) * 4;     // (e%32)/2
  const unsigned R32 = row >> 5, lo32 = row & 31;
  const size_t addr = (((size_t)(g2 << 8) + R32) << 10)
                    + (khalf * 32 + lo32) * 16 + byt;
  *(unsigned*)(Xq + addr) = ux;
  *(unsigned*)(Yq + addr) = uy;
  if (tid == 0) dg[row] = xy / (nx * ny);
}

// ---------- kernel 2: 128x128-tile MX-fp4 GEMM (32x32x64), NO LDS, NO barriers ----------
// Round-9 structure, mfma shape switched 16x16x128 -> 32x32x64: per k-group
// 8 mfma (vs 16) and half the operand-build VALU; loads identical. Natural
// block raster (round-11 8x8 raster reverted).
__global__ void __launch_bounds__(256) k_gemm(const unsigned char* __restrict__ Xq,
                                              const unsigned char* __restrict__ Yq,
                                              float* __restrict__ rowpart,
                                              float* __restrict__ colpart) {
  const int bm = blockIdx.x & (NTILE - 1);
  const int bn = blockIdx.x >> 6;
  const int tileRow = bm * 128;
  const int tileCol = bn * 128;

  __shared__ float rsum2[2][128];
  __shared__ float csum2[2][128];

  const int tid = threadIdx.x;
  const int lane = tid & 63;
  const int w = tid >> 6;        // wave 0..3
  const int wr = w >> 1;         // wave row 0..1  (64-row sub-tile)
  const int wc = w & 1;          // wave col 0..1  (64-col sub-tile)
  const int l31 = lane & 31;
  const int hi2 = lane >> 5;

  f32x16 acc[2][2];
#pragma unroll
  for (int mi = 0; mi < 2; ++mi)
#pragma unroll
    for (int ni = 0; ni < 2; ++ni)
#pragma unroll
      for (int q = 0; q < 16; ++q) acc[mi][ni][q] = 0.f;

  // per-wave fragment bases: A row-blocks R32 = bm*4 + wr*2 + mi,
  //                          B row-blocks R32 = bn*4 + wc*2 + ni
  const unsigned char* Ab = Xq + (((size_t)(bm * 4 + wr * 2)) << 10) + lane * 16;
  const unsigned char* Bb = Yq + (((size_t)(bn * 4 + wc * 2)) << 10) + lane * 16;

  // k-group g covers g2 = 2g (frags [0],[1] = mi/ni 0,1) and 2g+1 ([2],[3])
#define LOADF(da, db, g) do {                                                  \
    const unsigned char* pa_ = Ab + ((size_t)(2 * (g)) << 18);                 \
    const unsigned char* pb_ = Bb + ((size_t)(2 * (g)) << 18);                 \
    da[0] = *(const i32x4*)(pa_);                                              \
    da[1] = *(const i32x4*)(pa_ + 1024);                                       \
    da[2] = *(const i32x4*)(pa_ + (1 << 18));                                  \
    da[3] = *(const i32x4*)(pa_ + (1 << 18) + 1024);                           \
    db[0] = *(const i32x4*)(pb_);                                              \
    db[1] = *(const i32x4*)(pb_ + 1024);                                       \
    db[2] = *(const i32x4*)(pb_ + (1 << 18));                                  \
    db[3] = *(const i32x4*)(pb_ + (1 << 18) + 1024);                           \
  } while (0)

#define MM(aa, bb) do {                                                        \
    _Pragma("unroll")                                                          \
    for (int kk_ = 0; kk_ < 2; ++kk_)                                          \
      _Pragma("unroll")                                                        \
      for (int mi_ = 0; mi_ < 2; ++mi_) {                                      \
        i32x8 av_ = {aa[kk_*2+mi_][0], aa[kk_*2+mi_][1],                       \
                     aa[kk_*2+mi_][2], aa[kk_*2+mi_][3], 0, 0, 0, 0};          \
        _Pragma("unroll")                                                      \
        for (int ni_ = 0; ni_ < 2; ++ni_) {                                    \
          i32x8 bv_ = {bb[kk_*2+ni_][0], bb[kk_*2+ni_][1],                     \
                       bb[kk_*2+ni_][2], bb[kk_*2+ni_][3], 0, 0, 0, 0};        \
          acc[mi_][ni_] = __builtin_amdgcn_mfma_scale_f32_32x32x64_f8f6f4(     \
              av_, bv_, acc[mi_][ni_], 4, 4, 0, SCALE_I32, 0, SCALE_I32);      \
        }                                                                      \
      }                                                                        \
  } while (0)

  i32x4 a0[4], b0[4], a1[4], b1[4];
  LOADF(a0, b0, 0);
  for (int g = 0; g < NKG; g += 2) {
    LOADF(a1, b1, g + 1);
    MM(a0, b0);
    if (g + 2 < NKG) LOADF(a0, b0, g + 2);
    MM(a1, b1);
  }
#undef LOADF
#undef MM

  // ---- epilogue: exp + per-tile row/col sums ----
  // 32x32 C/D layout: col = lane&31, row = (reg&3) + 8*(reg>>2) + 4*(lane>>5)
  float rp[2][16];
  float cp[2];
#pragma unroll
  for (int mi = 0; mi < 2; ++mi)
#pragma unroll
    for (int r = 0; r < 16; ++r) rp[mi][r] = 0.f;
  cp[0] = 0.f; cp[1] = 0.f;

#pragma unroll
  for (int mi = 0; mi < 2; ++mi)
#pragma unroll
    for (int ni = 0; ni < 2; ++ni)
#pragma unroll
      for (int r = 0; r < 16; ++r) {
        float e = __expf(acc[mi][ni][r]);
        rp[mi][r] += e;
        cp[ni] += e;
      }

  // row sums: reduce across the 32 cols (lanes sharing hi2)
#pragma unroll
  for (int mi = 0; mi < 2; ++mi)
#pragma unroll
    for (int r = 0; r < 16; ++r) {
      float v = rp[mi][r];
      v += __shfl_xor(v, 1);
      v += __shfl_xor(v, 2);
      v += __shfl_xor(v, 4);
      v += __shfl_xor(v, 8);
      v += __shfl_xor(v, 16);
      rp[mi][r] = v;
    }
  // col sums: merge the two row-quarter halves (hi2)
  cp[0] += __shfl_xor(cp[0], 32);
  cp[1] += __shfl_xor(cp[1], 32);

  if (l31 == 0) {
#pragma unroll
    for (int mi = 0; mi < 2; ++mi)
#pragma unroll
      for (int r = 0; r < 16; ++r) {
        int lrow = wr * 64 + mi * 32 + (r & 3) + 8 * (r >> 2) + 4 * hi2;
        rsum2[wc][lrow] = rp[mi][r];
      }
  }
  if (hi2 == 0) {
#pragma unroll
    for (int ni = 0; ni < 2; ++ni)
      csum2[wr][wc * 64 + ni * 32 + l31] = cp[ni];
  }
  __syncthreads();

  if (tid < 128) {
    rowpart[(size_t)bn * BSZ + tileRow + tid] = rsum2[0][tid] + rsum2[1][tid];
    colpart[(size_t)bm * BSZ + tileCol + tid] = csum2[0][tid] + csum2[1][tid];
  }
}

// ---------- kernel 3: reduce partials + final expression ----------
__global__ void __launch_bounds__(256) k_final(const float* __restrict__ rowpart,
                                               const float* __restrict__ colpart,
                                               const float* __restrict__ dg,
                                               float* __restrict__ out) {
  const int k = blockIdx.x * 256 + threadIdx.x;
  float rs = 0.f, cs = 0.f;
#pragma unroll 8
  for (int s = 0; s < NTILE; ++s) {
    rs += rowpart[(size_t)s * BSZ + k];
    cs += colpart[(size_t)s * BSZ + k];
  }
  float d = dg[k];
  float p = __expf(d);
  out[k] = logf(cs - p) + logf(rs - p) - 2.0f * d;
}

extern "C" void kernel_launch(void* const* d_in, const int* in_sizes, int n_in,
                              void* d_out, int out_size, void* d_ws, size_t ws_size,
                              hipStream_t stream) {
  const float* X = (const float*)d_in[0];
  const float* Y = (const float*)d_in[1];
  float* out = (float*)d_out;

  char* ws = (char*)d_ws;
  // layout: Xq (8MB) | Yq (8MB) | diag (32KB) | rowpart (2MB) | colpart (2MB)
  unsigned char* Xq = (unsigned char*)ws;
  unsigned char* Yq = (unsigned char*)(ws + (size_t)BSZ * DIM / 2);
  float* diag = (float*)(ws + (size_t)BSZ * DIM);
  float* rowpart = (float*)(ws + (size_t)BSZ * DIM + BSZ * 4);
  float* colpart = (float*)(ws + (size_t)BSZ * DIM + BSZ * 4 + (size_t)NTILE * BSZ * 4);

  k_prep<<<BSZ, 256, 0, stream>>>(X, Y, Xq, Yq, diag);
  k_gemm<<<NTILE * NTILE, 256, 0, stream>>>(Xq, Yq, rowpart, colpart);
  k_final<<<BSZ / 256, 256, 0, stream>>>(rowpart, colpart, diag, out);
}

// Round 13
// 133.594 us; speedup vs baseline: 1.0415x; 1.0415x over previous
//
#include <hip/hip_runtime.h>
#include <hip/hip_bf16.h>
#include <math.h>

typedef float f32x4 __attribute__((ext_vector_type(4)));
typedef int   i32x4 __attribute__((ext_vector_type(4)));
typedef int   i32x8 __attribute__((ext_vector_type(8)));

#define BSZ 8192
#define DIM 2048
#define NTILE 64           // 8192 / 128 tiles per side
#define NKG 16             // k-groups of 128 elements

// MX e8m0 scale byte for 2^-6 (inputs pre-scaled by 64): 127-6 = 121 = 0x79
#define SCALE_I32 0x79797979

// Fragment-major fp4 layout:
//   frag(g, R) = 1024 B, g = k/128 (0..15), R = row/16 (0..511)
//   frag base byte = ((g << 9) + R) << 10
//   within frag: lane (lo = row&15, hi = (k%128)/32) at byte (hi*16+lo)*16,
//   holding row R*16+lo, k elems g*128 + hi*32 .. +31 (2 elems/byte, ascending)
// One global_load_dwordx4 per lane = one fragment, fully coalesced (1 KB).

// ---------- e2m1 fp4 encode (round to nearest) ----------
__device__ __forceinline__ unsigned f2fp4(float v) {
  float a = fabsf(v);
  unsigned s = (__float_as_uint(v) >> 31) << 3;
  unsigned m = (a < 0.25f) ? 0u
             : (a < 0.75f) ? 1u
             : (a < 1.25f) ? 2u
             : (a < 1.75f) ? 3u
             : (a < 2.5f)  ? 4u
             : (a < 3.5f)  ? 5u
             : (a < 5.0f)  ? 6u : 7u;
  return s | m;
}

// ---------- kernel 1: fused normalize -> fp4(x*64) in fragment order, diag ----------
__global__ void __launch_bounds__(256) k_prep(const float* __restrict__ X,
                                              const float* __restrict__ Y,
                                              unsigned char* __restrict__ Xq,
                                              unsigned char* __restrict__ Yq,
                                              float* __restrict__ dg) {
  const int row = blockIdx.x;
  const int tid = threadIdx.x;
  const float4* xp = (const float4*)(X + (size_t)row * DIM);
  const float4* yp = (const float4*)(Y + (size_t)row * DIM);
  float4 x0 = xp[tid * 2], x1 = xp[tid * 2 + 1];
  float4 y0 = yp[tid * 2], y1 = yp[tid * 2 + 1];
  float sxx = x0.x*x0.x + x0.y*x0.y + x0.z*x0.z + x0.w*x0.w
            + x1.x*x1.x + x1.y*x1.y + x1.z*x1.z + x1.w*x1.w;
  float syy = y0.x*y0.x + y0.y*y0.y + y0.z*y0.z + y0.w*y0.w
            + y1.x*y1.x + y1.y*y1.y + y1.z*y1.z + y1.w*y1.w;
  float sxy = x0.x*y0.x + x0.y*y0.y + x0.z*y0.z + x0.w*y0.w
            + x1.x*y1.x + x1.y*y1.y + x1.z*y1.z + x1.w*y1.w;
#pragma unroll
  for (int m = 32; m >= 1; m >>= 1) {
    sxx += __shfl_xor(sxx, m);
    syy += __shfl_xor(syy, m);
    sxy += __shfl_xor(sxy, m);
  }
  __shared__ float sh[3][4];
  if ((tid & 63) == 0) {
    sh[0][tid >> 6] = sxx; sh[1][tid >> 6] = syy; sh[2][tid >> 6] = sxy;
  }
  __syncthreads();
  float xx = sh[0][0] + sh[0][1] + sh[0][2] + sh[0][3];
  float yy = sh[1][0] + sh[1][1] + sh[1][2] + sh[1][3];
  float xy = sh[2][0] + sh[2][1] + sh[2][2] + sh[2][3];
  float nx = fmaxf(sqrtf(xx), 1e-8f);
  float ny = fmaxf(sqrtf(yy), 1e-8f);
  float ix = 64.0f / nx, iy = 64.0f / ny;   // x64 pre-scale onto e2m1 grid
  float vx[8] = {x0.x, x0.y, x0.z, x0.w, x1.x, x1.y, x1.z, x1.w};
  float vy[8] = {y0.x, y0.y, y0.z, y0.w, y1.x, y1.y, y1.z, y1.w};
  unsigned ux = 0, uy = 0;
#pragma unroll
  for (int i = 0; i < 8; ++i) {
    ux |= f2fp4(vx[i] * ix) << (4 * i);
    uy |= f2fp4(vy[i] * iy) << (4 * i);
  }
  // thread tid covers elems e = tid*8 .. +7 of this row
  const unsigned kkg = tid >> 4;            // e/128
  const unsigned hi4 = (tid >> 2) & 3;      // (e%128)/32
  const unsigned byt = (tid & 3) * 4;       // (e%32)/2
  const unsigned R = row >> 4, lo16 = row & 15;
  const size_t addr = (((size_t)(kkg << 9) + R) << 10) + (hi4 * 16 + lo16) * 16 + byt;
  *(unsigned*)(Xq + addr) = ux;
  *(unsigned*)(Yq + addr) = uy;
  if (tid == 0) dg[row] = xy / (nx * ny);
}

// ---------- kernel 2: 128x128-tile MX-fp4 GEMM, NO LDS, NO barriers ----------
// Round-9 verified kernel (93.5 us) with ONE change: __launch_bounds__(256, 4)
// caps total regs at 128/wave (64 AGPR acc + <=64 arch VGPR) -> 4 waves/SIMD
// instead of 3. Trades per-wave load-pipeline depth for +33% TLP stall
// coverage. Natural block raster; 16x16x128 mfma (32x32x64 reverted, r12).
__global__ void __launch_bounds__(256, 4) k_gemm(const unsigned char* __restrict__ Xq,
                                                 const unsigned char* __restrict__ Yq,
                                                 float* __restrict__ rowpart,
                                                 float* __restrict__ colpart) {
  const int bm = blockIdx.x & (NTILE - 1);
  const int bn = blockIdx.x >> 6;
  const int tileRow = bm * 128;
  const int tileCol = bn * 128;

  __shared__ float rsum2[2][128];
  __shared__ float csum2[2][128];

  const int tid = threadIdx.x;
  const int lane = tid & 63;
  const int w = tid >> 6;        // wave 0..3
  const int wr = w >> 1;         // wave row 0..1  (64-row sub-tile)
  const int wc = w & 1;          // wave col 0..1  (64-col sub-tile)
  const int lo = lane & 15;
  const int hi = lane >> 4;

  f32x4 acc[4][4];
#pragma unroll
  for (int m = 0; m < 4; ++m)
#pragma unroll
    for (int n = 0; n < 4; ++n) acc[m][n] = (f32x4){0.f, 0.f, 0.f, 0.f};

  // per-wave fragment base: A row-blocks bm*8 + wr*4 + m, B: bn*8 + wc*4 + n
  const unsigned char* Ab = Xq + (((size_t)(bm * 8 + wr * 4)) << 10) + lane * 16;
  const unsigned char* Bb = Yq + (((size_t)(bn * 8 + wc * 4)) << 10) + lane * 16;

#define LOADF(da, db, g) do {                                                  \
    const unsigned char* pa_ = Ab + ((size_t)(g) << 19);                       \
    const unsigned char* pb_ = Bb + ((size_t)(g) << 19);                       \
    da[0] = *(const i32x4*)(pa_);                                              \
    da[1] = *(const i32x4*)(pa_ + 1024);                                       \
    da[2] = *(const i32x4*)(pa_ + 2048);                                       \
    da[3] = *(const i32x4*)(pa_ + 3072);                                       \
    db[0] = *(const i32x4*)(pb_);                                              \
    db[1] = *(const i32x4*)(pb_ + 1024);                                       \
    db[2] = *(const i32x4*)(pb_ + 2048);                                       \
    db[3] = *(const i32x4*)(pb_ + 3072);                                       \
  } while (0)

#define MM(aa, bb) do {                                                        \
    _Pragma("unroll")                                                          \
    for (int m_ = 0; m_ < 4; ++m_) {                                           \
      i32x8 av_ = {aa[m_][0], aa[m_][1], aa[m_][2], aa[m_][3], 0, 0, 0, 0};    \
      _Pragma("unroll")                                                        \
      for (int n_ = 0; n_ < 4; ++n_) {                                         \
        i32x8 bv_ = {bb[n_][0], bb[n_][1], bb[n_][2], bb[n_][3], 0, 0, 0, 0};  \
        acc[m_][n_] = __builtin_amdgcn_mfma_scale_f32_16x16x128_f8f6f4(        \
            av_, bv_, acc[m_][n_], 4, 4, 0, SCALE_I32, 0, SCALE_I32);          \
      }                                                                        \
    }                                                                          \
  } while (0)

  i32x4 a0[4], b0[4], a1[4], b1[4];
  LOADF(a0, b0, 0);
  for (int g = 0; g < NKG; g += 2) {
    LOADF(a1, b1, g + 1);
    MM(a0, b0);
    if (g + 2 < NKG) LOADF(a0, b0, g + 2);
    MM(a1, b1);
  }
#undef LOADF
#undef MM

  // ---- epilogue: exp + per-tile row/col sums ----
  // D layout (16x16 shapes): row = m*16 + hi*4 + q, col = n*16 + lo
  float rp[4][4];
  float cp[4];
#pragma unroll
  for (int m = 0; m < 4; ++m)
#pragma unroll
    for (int q = 0; q < 4; ++q) rp[m][q] = 0.f;
#pragma unroll
  for (int n = 0; n < 4; ++n) cp[n] = 0.f;

#pragma unroll
  for (int m = 0; m < 4; ++m)
#pragma unroll
    for (int n = 0; n < 4; ++n)
#pragma unroll
      for (int q = 0; q < 4; ++q) {
        float e = __expf(acc[m][n][q]);
        rp[m][q] += e;
        cp[n] += e;
      }

#pragma unroll
  for (int m = 0; m < 4; ++m)
#pragma unroll
    for (int q = 0; q < 4; ++q) {
      float v = rp[m][q];
      v += __shfl_xor(v, 1);
      v += __shfl_xor(v, 2);
      v += __shfl_xor(v, 4);
      v += __shfl_xor(v, 8);
      rp[m][q] = v;
    }
#pragma unroll
  for (int n = 0; n < 4; ++n) {
    float v = cp[n];
    v += __shfl_xor(v, 16);
    v += __shfl_xor(v, 32);
    cp[n] = v;
  }

  if (lo == 0) {
#pragma unroll
    for (int m = 0; m < 4; ++m)
#pragma unroll
      for (int q = 0; q < 4; ++q)
        rsum2[wc][wr * 64 + m * 16 + hi * 4 + q] = rp[m][q];
  }
  if (hi == 0) {
#pragma unroll
    for (int n = 0; n < 4; ++n)
      csum2[wr][wc * 64 + n * 16 + lo] = cp[n];
  }
  __syncthreads();

  if (tid < 128) {
    rowpart[(size_t)bn * BSZ + tileRow + tid] = rsum2[0][tid] + rsum2[1][tid];
    colpart[(size_t)bm * BSZ + tileCol + tid] = csum2[0][tid] + csum2[1][tid];
  }
}

// ---------- kernel 3: reduce partials + final expression ----------
__global__ void __launch_bounds__(256) k_final(const float* __restrict__ rowpart,
                                               const float* __restrict__ colpart,
                                               const float* __restrict__ dg,
                                               float* __restrict__ out) {
  const int k = blockIdx.x * 256 + threadIdx.x;
  float rs = 0.f, cs = 0.f;
#pragma unroll 8
  for (int s = 0; s < NTILE; ++s) {
    rs += rowpart[(size_t)s * BSZ + k];
    cs += colpart[(size_t)s * BSZ + k];
  }
  float d = dg[k];
  float p = __expf(d);
  out[k] = logf(cs - p) + logf(rs - p) - 2.0f * d;
}

extern "C" void kernel_launch(void* const* d_in, const int* in_sizes, int n_in,
                              void* d_out, int out_size, void* d_ws, size_t ws_size,
                              hipStream_t stream) {
  const float* X = (const float*)d_in[0];
  const float* Y = (const float*)d_in[1];
  float* out = (float*)d_out;

  char* ws = (char*)d_ws;
  // layout: Xq (8MB) | Yq (8MB) | diag (32KB) | rowpart (2MB) | colpart (2MB)
  unsigned char* Xq = (unsigned char*)ws;
  unsigned char* Yq = (unsigned char*)(ws + (size_t)BSZ * DIM / 2);
  float* diag = (float*)(ws + (size_t)BSZ * DIM);
  float* rowpart = (float*)(ws + (size_t)BSZ * DIM + BSZ * 4);
  float* colpart = (float*)(ws + (size_t)BSZ * DIM + BSZ * 4 + (size_t)NTILE * BSZ * 4);

  k_prep<<<BSZ, 256, 0, stream>>>(X, Y, Xq, Yq, diag);
  k_gemm<<<NTILE * NTILE, 256, 0, stream>>>(Xq, Yq, rowpart, colpart);
  k_final<<<BSZ / 256, 256, 0, stream>>>(rowpart, colpart, diag, out);
}

// Round 14
// 121.049 us; speedup vs baseline: 1.1494x; 1.1036x over previous
//
#include <hip/hip_runtime.h>
#include <hip/hip_bf16.h>
#include <math.h>

typedef float f32x4 __attribute__((ext_vector_type(4)));
typedef int   i32x4 __attribute__((ext_vector_type(4)));
typedef int   i32x8 __attribute__((ext_vector_type(8)));

#define BSZ 8192
#define DIM 2048
#define NTM 64             // 8192 / 128 row tiles
#define NTN 32             // 8192 / 256 col tiles
#define NKG 16             // k-groups of 128 elements

// MX e8m0 scale byte for 2^-6 (inputs pre-scaled by 64): 127-6 = 121 = 0x79
#define SCALE_I32 0x79797979

// Fragment-major fp4 layout (unchanged from round 9):
//   frag(g, R) = 1024 B, g = k/128 (0..15), R = row/16 (0..511)
//   frag base byte = ((g << 9) + R) << 10
//   lane (lo = row&15, hi = (k%128)/32) at byte (hi*16+lo)*16
// One global_load_dwordx4 per lane = one fragment, fully coalesced (1 KB).

// ---------- e2m1 fp4 encode (round to nearest) ----------
__device__ __forceinline__ unsigned f2fp4(float v) {
  float a = fabsf(v);
  unsigned s = (__float_as_uint(v) >> 31) << 3;
  unsigned m = (a < 0.25f) ? 0u
             : (a < 0.75f) ? 1u
             : (a < 1.25f) ? 2u
             : (a < 1.75f) ? 3u
             : (a < 2.5f)  ? 4u
             : (a < 3.5f)  ? 5u
             : (a < 5.0f)  ? 6u : 7u;
  return s | m;
}

// ---------- kernel 1: fused normalize -> fp4(x*64) in fragment order, diag ----------
__global__ void __launch_bounds__(256) k_prep(const float* __restrict__ X,
                                              const float* __restrict__ Y,
                                              unsigned char* __restrict__ Xq,
                                              unsigned char* __restrict__ Yq,
                                              float* __restrict__ dg) {
  const int row = blockIdx.x;
  const int tid = threadIdx.x;
  const float4* xp = (const float4*)(X + (size_t)row * DIM);
  const float4* yp = (const float4*)(Y + (size_t)row * DIM);
  float4 x0 = xp[tid * 2], x1 = xp[tid * 2 + 1];
  float4 y0 = yp[tid * 2], y1 = yp[tid * 2 + 1];
  float sxx = x0.x*x0.x + x0.y*x0.y + x0.z*x0.z + x0.w*x0.w
            + x1.x*x1.x + x1.y*x1.y + x1.z*x1.z + x1.w*x1.w;
  float syy = y0.x*y0.x + y0.y*y0.y + y0.z*y0.z + y0.w*y0.w
            + y1.x*y1.x + y1.y*y1.y + y1.z*y1.z + y1.w*y1.w;
  float sxy = x0.x*y0.x + x0.y*y0.y + x0.z*y0.z + x0.w*y0.w
            + x1.x*y1.x + x1.y*y1.y + x1.z*y1.z + x1.w*y1.w;
#pragma unroll
  for (int m = 32; m >= 1; m >>= 1) {
    sxx += __shfl_xor(sxx, m);
    syy += __shfl_xor(syy, m);
    sxy += __shfl_xor(sxy, m);
  }
  __shared__ float sh[3][4];
  if ((tid & 63) == 0) {
    sh[0][tid >> 6] = sxx; sh[1][tid >> 6] = syy; sh[2][tid >> 6] = sxy;
  }
  __syncthreads();
  float xx = sh[0][0] + sh[0][1] + sh[0][2] + sh[0][3];
  float yy = sh[1][0] + sh[1][1] + sh[1][2] + sh[1][3];
  float xy = sh[2][0] + sh[2][1] + sh[2][2] + sh[2][3];
  float nx = fmaxf(sqrtf(xx), 1e-8f);
  float ny = fmaxf(sqrtf(yy), 1e-8f);
  float ix = 64.0f / nx, iy = 64.0f / ny;   // x64 pre-scale onto e2m1 grid
  float vx[8] = {x0.x, x0.y, x0.z, x0.w, x1.x, x1.y, x1.z, x1.w};
  float vy[8] = {y0.x, y0.y, y0.z, y0.w, y1.x, y1.y, y1.z, y1.w};
  unsigned ux = 0, uy = 0;
#pragma unroll
  for (int i = 0; i < 8; ++i) {
    ux |= f2fp4(vx[i] * ix) << (4 * i);
    uy |= f2fp4(vy[i] * iy) << (4 * i);
  }
  const unsigned kkg = tid >> 4;            // e/128
  const unsigned hi4 = (tid >> 2) & 3;      // (e%128)/32
  const unsigned byt = (tid & 3) * 4;       // (e%32)/2
  const unsigned R = row >> 4, lo16 = row & 15;
  const size_t addr = (((size_t)(kkg << 9) + R) << 10) + (hi4 * 16 + lo16) * 16 + byt;
  *(unsigned*)(Xq + addr) = ux;
  *(unsigned*)(Yq + addr) = uy;
  if (tid == 0) dg[row] = xy / (nx * ny);
}

// ---------- kernel 2: 128x256-block MX-fp4 GEMM, NO LDS, NO barriers ----------
// Round-9 structure with the wave tile grown 64x64 -> 64x128: per k-group
// 12 fragment loads (4 A + 8 B) feed 32 mfma (0.375 KB/mfma vs 0.5), L2
// traffic -25%, operand-build VALU per mfma halved. acc = 128 AGPR ->
// ~2 waves/SIMD; per-SIMD outstanding loads unchanged (2x12 vs 3x8).
__global__ void __launch_bounds__(256) k_gemm(const unsigned char* __restrict__ Xq,
                                              const unsigned char* __restrict__ Yq,
                                              float* __restrict__ rowpart,
                                              float* __restrict__ colpart) {
  const int bm = blockIdx.x & (NTM - 1);   // 128-row tile
  const int bn = blockIdx.x >> 6;          // 256-col tile (0..31)
  const int tileRow = bm * 128;
  const int tileCol = bn * 256;

  __shared__ float rsum2[2][128];
  __shared__ float csum2[2][256];

  const int tid = threadIdx.x;
  const int lane = tid & 63;
  const int w = tid >> 6;        // wave 0..3
  const int wr = w >> 1;         // row half (64 rows)
  const int wc = w & 1;          // col half (128 cols)
  const int lo = lane & 15;
  const int hi = lane >> 4;

  f32x4 acc[4][8];
#pragma unroll
  for (int m = 0; m < 4; ++m)
#pragma unroll
    for (int n = 0; n < 8; ++n) acc[m][n] = (f32x4){0.f, 0.f, 0.f, 0.f};

  // A: R-blocks bm*8 + wr*4 + m (m 0..3); B: R-blocks bn*16 + wc*8 + n (n 0..7)
  const unsigned char* Ab = Xq + (((size_t)(bm * 8 + wr * 4)) << 10) + lane * 16;
  const unsigned char* Bb = Yq + (((size_t)(bn * 16 + wc * 8)) << 10) + lane * 16;

#define LOADF(da, db, g) do {                                                  \
    const unsigned char* pa_ = Ab + ((size_t)(g) << 19);                       \
    const unsigned char* pb_ = Bb + ((size_t)(g) << 19);                       \
    _Pragma("unroll")                                                          \
    for (int m_ = 0; m_ < 4; ++m_) da[m_] = *(const i32x4*)(pa_ + m_ * 1024);  \
    _Pragma("unroll")                                                          \
    for (int n_ = 0; n_ < 8; ++n_) db[n_] = *(const i32x4*)(pb_ + n_ * 1024);  \
  } while (0)

#define MM(aa, bb) do {                                                        \
    _Pragma("unroll")                                                          \
    for (int m_ = 0; m_ < 4; ++m_) {                                           \
      i32x8 av_ = {aa[m_][0], aa[m_][1], aa[m_][2], aa[m_][3], 0, 0, 0, 0};    \
      _Pragma("unroll")                                                        \
      for (int n_ = 0; n_ < 8; ++n_) {                                         \
        i32x8 bv_ = {bb[n_][0], bb[n_][1], bb[n_][2], bb[n_][3], 0, 0, 0, 0};  \
        acc[m_][n_] = __builtin_amdgcn_mfma_scale_f32_16x16x128_f8f6f4(        \
            av_, bv_, acc[m_][n_], 4, 4, 0, SCALE_I32, 0, SCALE_I32);          \
      }                                                                        \
    }                                                                          \
  } while (0)

  i32x4 a0[4], b0[8], a1[4], b1[8];
  LOADF(a0, b0, 0);
  for (int g = 0; g < NKG; g += 2) {
    LOADF(a1, b1, g + 1);
    MM(a0, b0);
    if (g + 2 < NKG) LOADF(a0, b0, g + 2);
    MM(a1, b1);
  }
#undef LOADF
#undef MM

  // ---- epilogue: exp + per-tile row/col sums ----
  // D layout: row = wr*64 + m*16 + hi*4 + q, col = wc*128 + n*16 + lo
  float rp[4][4];
  float cp[8];
#pragma unroll
  for (int m = 0; m < 4; ++m)
#pragma unroll
    for (int q = 0; q < 4; ++q) rp[m][q] = 0.f;
#pragma unroll
  for (int n = 0; n < 8; ++n) cp[n] = 0.f;

#pragma unroll
  for (int m = 0; m < 4; ++m)
#pragma unroll
    for (int n = 0; n < 8; ++n)
#pragma unroll
      for (int q = 0; q < 4; ++q) {
        float e = __expf(acc[m][n][q]);
        rp[m][q] += e;
        cp[n] += e;
      }

#pragma unroll
  for (int m = 0; m < 4; ++m)
#pragma unroll
    for (int q = 0; q < 4; ++q) {
      float v = rp[m][q];
      v += __shfl_xor(v, 1);
      v += __shfl_xor(v, 2);
      v += __shfl_xor(v, 4);
      v += __shfl_xor(v, 8);
      rp[m][q] = v;
    }
#pragma unroll
  for (int n = 0; n < 8; ++n) {
    float v = cp[n];
    v += __shfl_xor(v, 16);
    v += __shfl_xor(v, 32);
    cp[n] = v;
  }

  if (lo == 0) {
#pragma unroll
    for (int m = 0; m < 4; ++m)
#pragma unroll
      for (int q = 0; q < 4; ++q)
        rsum2[wc][wr * 64 + m * 16 + hi * 4 + q] = rp[m][q];
  }
  if (hi == 0) {
#pragma unroll
    for (int n = 0; n < 8; ++n)
      csum2[wr][wc * 128 + n * 16 + lo] = cp[n];
  }
  __syncthreads();

  if (tid < 128)
    rowpart[(size_t)bn * BSZ + tileRow + tid] = rsum2[0][tid] + rsum2[1][tid];
  colpart[(size_t)bm * BSZ + tileCol + tid] = csum2[0][tid] + csum2[1][tid];
}

// ---------- kernel 3: reduce partials + final expression ----------
__global__ void __launch_bounds__(256) k_final(const float* __restrict__ rowpart,
                                               const float* __restrict__ colpart,
                                               const float* __restrict__ dg,
                                               float* __restrict__ out) {
  const int k = blockIdx.x * 256 + threadIdx.x;
  float rs = 0.f, cs = 0.f;
#pragma unroll 8
  for (int s = 0; s < NTN; ++s)
    rs += rowpart[(size_t)s * BSZ + k];
#pragma unroll 8
  for (int s = 0; s < NTM; ++s)
    cs += colpart[(size_t)s * BSZ + k];
  float d = dg[k];
  float p = __expf(d);
  out[k] = logf(cs - p) + logf(rs - p) - 2.0f * d;
}

extern "C" void kernel_launch(void* const* d_in, const int* in_sizes, int n_in,
                              void* d_out, int out_size, void* d_ws, size_t ws_size,
                              hipStream_t stream) {
  const float* X = (const float*)d_in[0];
  const float* Y = (const float*)d_in[1];
  float* out = (float*)d_out;

  char* ws = (char*)d_ws;
  // layout: Xq (8MB) | Yq (8MB) | diag (32KB) | rowpart (1MB) | colpart (2MB)
  unsigned char* Xq = (unsigned char*)ws;
  unsigned char* Yq = (unsigned char*)(ws + (size_t)BSZ * DIM / 2);
  float* diag = (float*)(ws + (size_t)BSZ * DIM);
  float* rowpart = (float*)(ws + (size_t)BSZ * DIM + BSZ * 4);
  float* colpart = (float*)(ws + (size_t)BSZ * DIM + BSZ * 4 + (size_t)NTN * BSZ * 4);

  k_prep<<<BSZ, 256, 0, stream>>>(X, Y, Xq, Yq, diag);
  k_gemm<<<NTM * NTN, 256, 0, stream>>>(Xq, Yq, rowpart, colpart);
  k_final<<<BSZ / 256, 256, 0, stream>>>(rowpart, colpart, diag, out);
}